// Round 8
// baseline (228.059 us; speedup 1.0000x reference)
//
#include <hip/hip_runtime.h>

// LJ pair energy -> segment-sum onto first atom of each pair, no fp atomics.
// Round-8: K1 writes records DIRECTLY to global (no LDS staging), K3 fused
// into K2 via last-block-per-bucket ticket.
//   K1 lj_bin (512 thr, CHUNK=8192): q = round(half_en(d)*2^15) (23b clamp),
//      bucket = atom>>9 (512 atoms/bucket, nb=196). rank = LDS atomicAdd on
//      cnt[256]; shfl scan -> offs; record (q<<9|local) stored straight to
//      grec[base+offs[b]+rank] (scattered 4B stores, line-merged in XCD-local
//      L2). Offset row in transposed layout goffs[(b*NS+s)*P + c/NS], s=c%NS.
//   K2 lj_red (grid vb = b*NS+s): slice s owns chunks c≡s (mod NS); with
//      round-robin blockIdx->XCD the reducer lands on the XCD whose L2 holds
//      its records. Preload lo/hi rows; 2x32 lane-split run gather; LDS int
//      acc[512]; write int partial[s]; ticket[b]: last of the NS blocks sums
//      the 8 partials and writes out floats (int sums => order-independent,
//      bit-deterministic).
// half_en(d) = 2*((1/d)^12 - (1/d)^6) - e0/2, e0/2 = -2.739720872119788e-3.
// |half_en| <= ~23.3 for d >= 0.8 -> |q| <= ~764k < 2^22 (23-bit field).

#define CHUNK 8192
#define T1 512
#define ABITS 9
#define APB 512             // atoms per bucket
#define QSCALE 32768.0f     // 2^15
#define QINV (1.0f / 32768.0f)
#define NS 8                // slices == XCD count
#define MAXCPS 160          // max chunks per slice (P)
#define T2 256

static __device__ __forceinline__ float half_en(float d) {
    const float half_e0 = -2.739720872119788e-3f;
    float inv = 1.0f / d;
    float i2 = inv * inv;
    float i6 = i2 * i2 * i2;
    return 2.0f * (i6 * i6 - i6) - half_e0;
}

static __device__ __forceinline__ int quant(float e) {
    int q = __float2int_rn(e * QSCALE);
    return max(-4194304, min(4194303, q));  // 23-bit signed
}

__global__ __launch_bounds__(T1) void lj_bin(const float* __restrict__ dist,
                                             const int* __restrict__ ind2,
                                             unsigned* __restrict__ grec,
                                             unsigned* __restrict__ goffs,
                                             int n_pairs, int nchunk, int nb, int P) {
    __shared__ unsigned cnt[256];
    __shared__ unsigned offs[256];
    __shared__ unsigned wsum[4];

    const int t = threadIdx.x;
    const int c = blockIdx.x;
    const int base = c * CHUNK;

    if (t < 256) cnt[t] = 0;
    __syncthreads();

    unsigned rec[16];
    unsigned br[16];  // (bucket<<16) | rank ; 0xFFFFFFFF = invalid

    #pragma unroll
    for (int g = 0; g < 4; ++g) {
        const int p0 = base + g * (T1 * 4) + t * 4;
        float dd[4] = {0.f, 0.f, 0.f, 0.f};
        int ii[4] = {0, 0, 0, 0};
        if (p0 + 4 <= n_pairs) {
            float4 d = *reinterpret_cast<const float4*>(dist + p0);
            int4 ia = *reinterpret_cast<const int4*>(ind2 + 2 * p0);
            int4 ib = *reinterpret_cast<const int4*>(ind2 + 2 * p0 + 4);
            dd[0] = d.x; dd[1] = d.y; dd[2] = d.z; dd[3] = d.w;
            ii[0] = ia.x; ii[1] = ia.z; ii[2] = ib.x; ii[3] = ib.z;
        } else {
            #pragma unroll
            for (int k = 0; k < 4; ++k)
                if (p0 + k < n_pairs) { dd[k] = dist[p0 + k]; ii[k] = ind2[2 * (p0 + k)]; }
        }
        #pragma unroll
        for (int k = 0; k < 4; ++k) {
            const int j = g * 4 + k;
            if (p0 + k < n_pairs) {
                const int id = ii[k];
                const int b = id >> ABITS;
                const int q = quant(half_en(dd[k]));
                rec[j] = (((unsigned)q) << ABITS) | (unsigned)(id & (APB - 1));
                const unsigned rank = atomicAdd(&cnt[b], 1u);  // rank within bucket
                br[j] = ((unsigned)b << 16) | rank;            // rank < 8192 fits
            } else {
                br[j] = 0xFFFFFFFFu;
                rec[j] = 0;
            }
        }
    }
    __syncthreads();

    // Exclusive scan of cnt[0..255]: per-wave shfl scan + wave-total fixup.
    {
        const unsigned v = (t < 256) ? cnt[t] : 0u;
        unsigned inc = v;
        #pragma unroll
        for (int d = 1; d < 64; d <<= 1) {
            const unsigned x = __shfl_up(inc, d, 64);
            if ((t & 63) >= d) inc += x;
        }
        if (t < 256 && (t & 63) == 63) wsum[t >> 6] = inc;
        __syncthreads();
        if (t < 256) {
            unsigned add = 0;
            #pragma unroll
            for (int j = 0; j < 4; ++j)
                if (j < (t >> 6)) add += wsum[j];
            offs[t] = add + inc - v;  // exclusive
        }
    }
    __syncthreads();

    // Store records straight to global, grouped by bucket inside the chunk
    // region (scattered 4B stores within a 32KB window; L2 line-merges).
    #pragma unroll
    for (int j = 0; j < 16; ++j) {
        if (br[j] != 0xFFFFFFFFu) {
            const unsigned pos = offs[br[j] >> 16] + (br[j] & 0xFFFFu);
            grec[(unsigned)base + pos] = rec[j];
        }
    }

    // Transposed offset row: (bucket t, slice s=c%NS), column cc=c/NS.
    // Row nb is the end sentinel (offs[nb] = chunk's valid count).
    if (t <= nb)
        goffs[((size_t)t * NS + (c & (NS - 1))) * P + (c >> 3)] = offs[t];
}

__global__ __launch_bounds__(T2) void lj_red(const unsigned* __restrict__ grec,
                                             const unsigned* __restrict__ goffs,
                                             int* __restrict__ partial,
                                             unsigned* __restrict__ ticket,
                                             float* __restrict__ out,
                                             int nchunk, int nb, int natom_pad,
                                             int natom, int P) {
    __shared__ int acc[APB];
    __shared__ unsigned lo[MAXCPS];
    __shared__ unsigned hi[MAXCPS];
    __shared__ int is_last;

    const int t = threadIdx.x;
    const int vb = blockIdx.x;
    const int s = vb & (NS - 1);   // slice -> same XCD as its chunks (heuristic)
    const int b = vb >> 3;         // NS == 8

    #pragma unroll
    for (int k = 0; k < APB / T2; ++k) acc[t + k * T2] = 0;

    // Slice s owns chunks c = s + NS*cc, cc in [0, cn).
    const int cn = (nchunk - s + NS - 1) >> 3;
    if (cn > 0) {
        const unsigned* r0 = goffs + ((size_t)b * NS + s) * P;
        const unsigned* r1 = goffs + ((size_t)(b + 1) * NS + s) * P;
        for (int i = t; i < cn; i += T2) { lo[i] = r0[i]; hi[i] = r1[i]; }
    }
    __syncthreads();

    if (cn > 0) {
        // Each wave handles TWO runs at once (lanes 0-31 / 32-63).
        const int wv = t >> 6;
        const int half = (t >> 5) & 1;
        const int sub = t & 31;
        for (int cc = wv * 2; cc < cn; cc += (T2 / 64) * 2) {
            const int myrun = cc + half;
            if (myrun < cn) {
                const unsigned o0 = lo[myrun];
                const unsigned o1 = hi[myrun];
                const size_t rb = (size_t)(s + myrun * NS) * CHUNK;
                for (unsigned i = o0 + sub; i < o1; i += 32) {
                    const unsigned r = grec[rb + i];
                    atomicAdd(&acc[r & (APB - 1)], ((int)r) >> ABITS);
                }
            }
        }
    }
    __syncthreads();

    int* mypart = partial + ((size_t)s * natom_pad + (size_t)b * APB);
    #pragma unroll
    for (int k = 0; k < APB / T2; ++k) mypart[t + k * T2] = acc[t + k * T2];

    // Last-done block of this bucket sums the NS partials and writes out.
    __threadfence();  // make partial[] visible device-wide (cross-XCD)
    if (t == 0) {
        const unsigned old = __hip_atomic_fetch_add(&ticket[b], 1u,
                                                    __ATOMIC_ACQ_REL,
                                                    __HIP_MEMORY_SCOPE_AGENT);
        is_last = (old == NS - 1);
    }
    __syncthreads();

    if (is_last) {
        __threadfence();  // acquire: see all other slices' partial writes
        #pragma unroll
        for (int k = 0; k < APB / T2; ++k) {
            const int idx = t + k * T2;
            const int a = b * APB + idx;
            if (a < natom) {
                int ssum = 0;
                #pragma unroll
                for (int ss = 0; ss < NS; ++ss)
                    ssum += __hip_atomic_load(&partial[(size_t)ss * natom_pad + a],
                                              __ATOMIC_RELAXED,
                                              __HIP_MEMORY_SCOPE_AGENT);
                out[a] = (float)ssum * QINV;
            }
        }
    }
}

// Fallback: direct device atomics if ws too small / shape unexpected.
__global__ void lj_scatter_direct(const float* __restrict__ dist,
                                  const int* __restrict__ ind2,
                                  float* __restrict__ out,
                                  int n_pairs) {
    int t = blockIdx.x * blockDim.x + threadIdx.x;
    int i = t * 4;
    if (i >= n_pairs) return;
    if (i + 4 <= n_pairs) {
        float4 d = *reinterpret_cast<const float4*>(dist + i);
        int4 ia = *reinterpret_cast<const int4*>(ind2 + 2 * i);
        int4 ib = *reinterpret_cast<const int4*>(ind2 + 2 * i + 4);
        atomicAdd(&out[ia.x], half_en(d.x));
        atomicAdd(&out[ia.z], half_en(d.y));
        atomicAdd(&out[ib.x], half_en(d.z));
        atomicAdd(&out[ib.z], half_en(d.w));
    } else {
        for (int p = i; p < n_pairs; ++p)
            atomicAdd(&out[ind2[2 * p]], half_en(dist[p]));
    }
}

extern "C" void kernel_launch(void* const* d_in, const int* in_sizes, int n_in,
                              void* d_out, int out_size, void* d_ws, size_t ws_size,
                              hipStream_t stream) {
    const float* dist = (const float*)d_in[0];
    // d_in[1] = ind_1: only its shape (natom == out_size) matters.
    const int* ind2 = (const int*)d_in[2];
    float* out = (float*)d_out;

    const int n_pairs = in_sizes[0];
    const int natom = out_size;

    const int nchunk = (n_pairs + CHUNK - 1) / CHUNK;
    const int nb = (natom + APB - 1) / APB;
    const int natom_pad = nb * APB;
    const int P = (nchunk + NS - 1) / NS;   // max chunks per slice

    const size_t rec_bytes = (size_t)nchunk * CHUNK * sizeof(unsigned);
    const size_t offs_bytes = (size_t)(nb + 1) * NS * P * sizeof(unsigned);
    const size_t part_bytes = (size_t)NS * natom_pad * sizeof(int);
    const size_t tick_bytes = (size_t)nb * sizeof(unsigned);
    const size_t need = rec_bytes + offs_bytes + part_bytes + tick_bytes;

    if (nb + 1 > 256 || P > MAXCPS || need > ws_size) {
        hipMemsetAsync(d_out, 0, (size_t)out_size * sizeof(float), stream);
        int n_threads = (n_pairs + 3) / 4;
        int grid = (n_threads + 255) / 256;
        lj_scatter_direct<<<grid, 256, 0, stream>>>(dist, ind2, out, n_pairs);
        return;
    }

    unsigned* grec = (unsigned*)d_ws;
    unsigned* goffs = (unsigned*)((char*)d_ws + rec_bytes);
    int* partial = (int*)((char*)d_ws + rec_bytes + offs_bytes);
    unsigned* ticket = (unsigned*)((char*)d_ws + rec_bytes + offs_bytes + part_bytes);

    hipMemsetAsync(ticket, 0, tick_bytes, stream);  // per-call: graph replays
    lj_bin<<<nchunk, T1, 0, stream>>>(dist, ind2, grec, goffs, n_pairs, nchunk, nb, P);
    lj_red<<<NS * nb, T2, 0, stream>>>(grec, goffs, partial, ticket, out,
                                       nchunk, nb, natom_pad, natom, P);
}